// Round 4
// baseline (434.563 us; speedup 1.0000x reference)
//
#include <hip/hip_runtime.h>

// Apply a 2x2 gate (d_in[1], row-major [[p00,p01],[p10,p11]]) on qubit axis
// TARGET=10 of a (2,)*24 + (4,) fp32 statevector (d_in[0]).
// Flat layout: axis-10 stride = 2^(23-10) * 4 = 32768 floats = 8192 float4s.
// out[lo] = p00*in[lo] + p01*in[hi]; out[hi] = p10*in[lo] + p11*in[hi].
//
// Memory-bound: 537 MB/launch. Kernel-only ~93us (dur_us 422 = ~330us
// harness poison fills + kernel) = 5.8 TB/s mixed R/W, 92% of the 6.29 TB/s
// float4-copy ceiling. Round-2 A/B (grid-stride + NT loads+stores): -26us
// regression, reverted. This round isolates NT STORES only on the round-1
// structure: write stream is pure streaming past L3, so `nt` should skip
// L2/L3 write-allocation competing with the read stream.

#define SVEC 8192u          // pair stride in float4 units (2^13)
#define NPAIRS_VEC 8388608u // (2^24 * 4 floats) / 4 per float4 / 2 per pair

typedef float f32x4 __attribute__((ext_vector_type(4)));

__global__ __launch_bounds__(256) void pauli_apply_kernel(
    const f32x4* __restrict__ in,
    const float* __restrict__ pauli,
    f32x4*       __restrict__ out)
{
    const float p00 = pauli[0];
    const float p01 = pauli[1];
    const float p10 = pauli[2];
    const float p11 = pauli[3];

    unsigned t = blockIdx.x * blockDim.x + threadIdx.x;   // [0, NPAIRS_VEC)
    // insert a 0 bit at position 13 -> lo index; hi = lo | (1<<13)
    unsigned lo = ((t >> 13) << 14) | (t & (SVEC - 1u));
    unsigned hi = lo + SVEC;

    f32x4 a = in[lo];   // plain cached loads (round-1 proven)
    f32x4 b = in[hi];

    f32x4 o0 = p00 * a + p01 * b;
    f32x4 o1 = p10 * a + p11 * b;

    __builtin_nontemporal_store(o0, &out[lo]);  // NT stores: the one new knob
    __builtin_nontemporal_store(o1, &out[hi]);
}

extern "C" void kernel_launch(void* const* d_in, const int* in_sizes, int n_in,
                              void* d_out, int out_size, void* d_ws, size_t ws_size,
                              hipStream_t stream) {
    const f32x4* in    = (const f32x4*)d_in[0];
    const float* pauli = (const float*)d_in[1];
    f32x4*       out   = (f32x4*)d_out;

    const unsigned block = 256u;
    const unsigned grid  = NPAIRS_VEC / block;  // 32768 blocks
    pauli_apply_kernel<<<grid, block, 0, stream>>>(in, pauli, out);
}

// Round 5
// 422.088 us; speedup vs baseline: 1.0296x; 1.0296x over previous
//
#include <hip/hip_runtime.h>

// Apply a 2x2 gate (d_in[1], row-major [[p00,p01],[p10,p11]]) on qubit axis
// TARGET=10 of a (2,)*24 + (4,) fp32 statevector (d_in[0]).
// Flat layout: axis-10 stride = 2^(23-10) * 4 = 32768 floats = 8192 float4s.
// out[lo] = p00*in[lo] + p01*in[hi]; out[hi] = p10*in[lo] + p11*in[hi].
//
// Memory-bound: 537 MB/launch, irreducible (bijective pair-mix, every byte
// read once + written once). Kernel-only ~93us = 5.8 TB/s mixed R/W = 92%
// of the 6.29 TB/s float4-copy ceiling. Headline dur_us ~422 includes
// ~330us of harness poison fills (2x 1.07GB @ ~165us) we cannot touch.
//
// A/B history:
//   R1 this structure:                 422.4 us  <- best
//   R2 grid-stride 2048 + NT ld+st:    449.6 us  (TLP loss + NT both hurt)
//   R3 revert:                         422.4 us  (confirmed)
//   R4 NT stores only:                 434.6 us  (NT stores alone -12us)
// One thread per float4-pair, 8.4M threads, plain cached ops = roofline.

#define SVEC 8192u          // pair stride in float4 units (2^13)
#define NPAIRS_VEC 8388608u // (2^24 * 4 floats) / 4 per float4 / 2 per pair

__global__ __launch_bounds__(256) void pauli_apply_kernel(
    const float4* __restrict__ in,
    const float*  __restrict__ pauli,
    float4*       __restrict__ out)
{
    const float p00 = pauli[0];
    const float p01 = pauli[1];
    const float p10 = pauli[2];
    const float p11 = pauli[3];

    unsigned t = blockIdx.x * blockDim.x + threadIdx.x;   // [0, NPAIRS_VEC)
    // insert a 0 bit at position 13 -> lo index; hi = lo | (1<<13)
    unsigned lo = ((t >> 13) << 14) | (t & (SVEC - 1u));
    unsigned hi = lo + SVEC;

    float4 a = in[lo];
    float4 b = in[hi];

    float4 o0, o1;
    o0.x = p00 * a.x + p01 * b.x;
    o0.y = p00 * a.y + p01 * b.y;
    o0.z = p00 * a.z + p01 * b.z;
    o0.w = p00 * a.w + p01 * b.w;
    o1.x = p10 * a.x + p11 * b.x;
    o1.y = p10 * a.y + p11 * b.y;
    o1.z = p10 * a.z + p11 * b.z;
    o1.w = p10 * a.w + p11 * b.w;

    out[lo] = o0;
    out[hi] = o1;
}

extern "C" void kernel_launch(void* const* d_in, const int* in_sizes, int n_in,
                              void* d_out, int out_size, void* d_ws, size_t ws_size,
                              hipStream_t stream) {
    const float4* in    = (const float4*)d_in[0];
    const float*  pauli = (const float*)d_in[1];
    float4*       out   = (float4*)d_out;

    const unsigned block = 256u;
    const unsigned grid  = NPAIRS_VEC / block;  // 32768 blocks
    pauli_apply_kernel<<<grid, block, 0, stream>>>(in, pauli, out);
}